// Round 1
// baseline (308.370 us; speedup 1.0000x reference)
//
#include <hip/hip_runtime.h>
#include <hip/hip_bf16.h>
#include <math.h>

#define NN 250000
#define CIN 32
#define COUT 32
#define KK 27
#define BN_EPS 1e-5f

// ---------------- Kernel 1: octree conv (gather + contraction) ----------------
// One thread per node. acc[32] in VGPRs. Weight indexed wave-uniformly -> s_load.
__global__ __launch_bounds__(256) void conv_kernel(
    const float* __restrict__ x,
    const int* __restrict__ neigh,
    const float* __restrict__ w,
    float* __restrict__ y)
{
    int n = blockIdx.x * 256 + threadIdx.x;
    bool valid = (n < NN);
    int nsafe = valid ? n : 0;

    // preload neighbor indices
    int idx[KK];
#pragma unroll
    for (int k = 0; k < KK; ++k) idx[k] = neigh[(size_t)nsafe * KK + k];

    float acc[COUT];
#pragma unroll
    for (int d = 0; d < COUT; ++d) acc[d] = 0.0f;

    for (int k = 0; k < KK; ++k) {
        const float4* xr = (const float4*)(x + (size_t)idx[k] * CIN);
        float4 xv[8];
#pragma unroll
        for (int j = 0; j < 8; ++j) xv[j] = xr[j];
        const float* wk = w + k * (CIN * COUT);
        const float* xs = (const float*)xv;
#pragma unroll
        for (int c = 0; c < CIN; ++c) {
            float xc = xs[c];
#pragma unroll
            for (int d = 0; d < COUT; ++d)
                acc[d] = fmaf(xc, wk[c * COUT + d], acc[d]);
        }
    }

    if (valid) {
        float4* yr = (float4*)(y + (size_t)n * COUT);
#pragma unroll
        for (int j = 0; j < 8; ++j) {
            float4 v;
            v.x = acc[j * 4 + 0];
            v.y = acc[j * 4 + 1];
            v.z = acc[j * 4 + 2];
            v.w = acc[j * 4 + 3];
            yr[j] = v;
        }
    }
}

// ---------------- Kernel 2: per-channel sum / sumsq ----------------
// ws[0..31] = sum, ws[32..63] = sumsq (atomic accumulation, pre-zeroed)
__global__ __launch_bounds__(256) void stats_kernel(
    const float* __restrict__ y, float* __restrict__ ws)
{
    int d = threadIdx.x & 31;
    int rib = threadIdx.x >> 5;  // 0..7 rows per block slice
    float s = 0.0f, q = 0.0f;
    for (int r = blockIdx.x * 8 + rib; r < NN; r += gridDim.x * 8) {
        float v = y[(size_t)r * COUT + d];
        s += v;
        q += v * v;
    }
    __shared__ float ls[8][32];
    __shared__ float lq[8][32];
    ls[rib][d] = s;
    lq[rib][d] = q;
    __syncthreads();
    if (threadIdx.x < 32) {
        float S = 0.0f, Q = 0.0f;
#pragma unroll
        for (int i = 0; i < 8; ++i) { S += ls[i][threadIdx.x]; Q += lq[i][threadIdx.x]; }
        atomicAdd(&ws[threadIdx.x], S);
        atomicAdd(&ws[32 + threadIdx.x], Q);
    }
}

// ---------------- Kernel 3: finalize scale/shift ----------------
// ws[64..95] = scale = rstd*gamma ; ws[96..127] = shift = beta - mean*scale
__global__ void finalize_kernel(
    const float* __restrict__ gamma, const float* __restrict__ beta,
    float* __restrict__ ws)
{
    int d = threadIdx.x;
    if (d < 32) {
        float invN = 1.0f / (float)NN;
        float mean = ws[d] * invN;
        float var = ws[32 + d] * invN - mean * mean;
        float rstd = rsqrtf(var + BN_EPS);
        float scale = rstd * gamma[d];
        ws[64 + d] = scale;
        ws[96 + d] = beta[d] - mean * scale;
    }
}

// ---------------- Kernel 4: BN + ELU elementwise (in place on y) ----------------
__global__ __launch_bounds__(256) void bn_elu_kernel(
    float* __restrict__ y, const float* __restrict__ ws)
{
    __shared__ float sc[32], sh[32];
    if (threadIdx.x < 32) {
        sc[threadIdx.x] = ws[64 + threadIdx.x];
        sh[threadIdx.x] = ws[96 + threadIdx.x];
    }
    __syncthreads();
    size_t i = (size_t)blockIdx.x * 256 + threadIdx.x;     // float4 index
    size_t total = (size_t)NN * COUT / 4;
    if (i >= total) return;
    int c0 = (int)((i * 4) & 31);
    float4 v = ((const float4*)y)[i];
    float r[4] = {v.x, v.y, v.z, v.w};
#pragma unroll
    for (int j = 0; j < 4; ++j) {
        float t = r[j] * sc[c0 + j] + sh[c0 + j];
        r[j] = (t > 0.0f) ? t : expm1f(t);
    }
    float4 o; o.x = r[0]; o.y = r[1]; o.z = r[2]; o.w = r[3];
    ((float4*)y)[i] = o;
}

extern "C" void kernel_launch(void* const* d_in, const int* in_sizes, int n_in,
                              void* d_out, int out_size, void* d_ws, size_t ws_size,
                              hipStream_t stream) {
    const float* x     = (const float*)d_in[0];
    const int*   neigh = (const int*)d_in[1];
    const float* w     = (const float*)d_in[2];
    const float* gamma = (const float*)d_in[3];
    const float* beta  = (const float*)d_in[4];
    float* y  = (float*)d_out;
    float* ws = (float*)d_ws;

    // zero the 64-float accumulator region (deterministic per call)
    hipMemsetAsync(ws, 0, 128 * sizeof(float), stream);

    int convBlocks = (NN + 255) / 256;
    conv_kernel<<<convBlocks, 256, 0, stream>>>(x, neigh, w, y);

    stats_kernel<<<512, 256, 0, stream>>>(y, ws);

    finalize_kernel<<<1, 32, 0, stream>>>(gamma, beta, ws);

    size_t total4 = (size_t)NN * COUT / 4;
    int eluBlocks = (int)((total4 + 255) / 256);
    bn_elu_kernel<<<eluBlocks, 256, 0, stream>>>(y, ws);
}

// Round 2
// 160.577 us; speedup vs baseline: 1.9204x; 1.9204x over previous
//
#include <hip/hip_runtime.h>
#include <hip/hip_bf16.h>
#include <math.h>

#define NN 250000
#define CIN 32
#define COUT 32
#define KK 27
#define BN_EPS 1e-5f

typedef __attribute__((ext_vector_type(8))) short bf16x8;
typedef __attribute__((ext_vector_type(4))) float f32x4;

// ws layout (bytes):
//   [0, 512)        stats: ws_f[0..31]=sum, [32..63]=sumsq, [64..95]=scale, [96..127]=shift
//   [512, 55808)    packed bf16 weight: [k][h][lane][j]  (27*2*64*8 ushorts)
//   [65536, +16MB)  bf16 x: [NN][32]
#define WS_WB_OFF   512
#define WS_XB_OFF   65536
#define WS_NEED     (WS_XB_OFF + (size_t)NN * CIN * 2)

static __device__ __forceinline__ unsigned short f2bf(float f) {
    unsigned int u = __float_as_uint(f);
    unsigned int r = (u + 0x7fffu + ((u >> 16) & 1u)) >> 16;  // RNE
    return (unsigned short)r;
}

// ---------------- convert x (f32) -> xb (bf16), 8 elems/thread ----------------
__global__ __launch_bounds__(256) void convert_x_kernel(
    const float* __restrict__ x, unsigned short* __restrict__ xb)
{
    size_t i = (size_t)blockIdx.x * 256 + threadIdx.x;  // 8-float chunk index
    size_t total = (size_t)NN * CIN / 8;
    if (i >= total) return;
    const float4* xp = (const float4*)x;
    float4 a = xp[i * 2], b = xp[i * 2 + 1];
    union { unsigned short u[8]; uint4 v; } o;
    o.u[0] = f2bf(a.x); o.u[1] = f2bf(a.y); o.u[2] = f2bf(a.z); o.u[3] = f2bf(a.w);
    o.u[4] = f2bf(b.x); o.u[5] = f2bf(b.y); o.u[6] = f2bf(b.z); o.u[7] = f2bf(b.w);
    ((uint4*)xb)[i] = o.v;
}

// ---------------- pack w into B-fragment order ----------------
// wbp[((k*2+h)*64 + lane)*8 + j] = bf16( w[k][c = (lane>>4)*8 + j][d = h*16 + (lane&15)] )
__global__ __launch_bounds__(256) void pack_w_kernel(
    const float* __restrict__ w, unsigned short* __restrict__ wbp)
{
    int tid = blockIdx.x * 256 + threadIdx.x;
    if (tid >= KK * 2 * 64 * 8) return;
    int j = tid & 7;
    int l = (tid >> 3) & 63;
    int h = (tid >> 9) & 1;
    int k = tid >> 10;
    int c = (l >> 4) * 8 + j;
    int d = h * 16 + (l & 15);
    wbp[tid] = f2bf(w[k * (CIN * COUT) + c * COUT + d]);
}

// ---------------- MFMA conv: 16 nodes/wave, 64 nodes/block ----------------
__global__ __launch_bounds__(256) void conv_mfma_kernel(
    const unsigned short* __restrict__ xb,
    const int* __restrict__ neigh,
    const unsigned short* __restrict__ wbp,
    float* __restrict__ y)
{
    __shared__ int lidx[64 * KK];
    int b0 = blockIdx.x * 64;
    // coalesced stage of this block's 64x27 neighbor indices
    for (int t = threadIdx.x; t < 64 * KK; t += 256) {
        long long g = (long long)b0 * KK + t;
        lidx[t] = (g < (long long)NN * KK) ? neigh[g] : 0;
    }
    __syncthreads();

    int lane = threadIdx.x & 63;
    int wid  = threadIdx.x >> 6;
    int row  = lane & 15;   // A-fragment: M row
    int grp  = lane >> 4;   // A/B-fragment: K chunk (8 elems)
    int nl   = wid * 16 + row;

    f32x4 acc0 = {0.f, 0.f, 0.f, 0.f};
    f32x4 acc1 = {0.f, 0.f, 0.f, 0.f};
    const bf16x8* wb = (const bf16x8*)wbp;

#pragma unroll
    for (int k = 0; k < KK; ++k) {
        int nidx = lidx[nl * KK + k];
        bf16x8 a = *(const bf16x8*)(xb + (size_t)nidx * CIN + grp * 8);
        bf16x8 bb0 = wb[(k * 2 + 0) * 64 + lane];
        bf16x8 bb1 = wb[(k * 2 + 1) * 64 + lane];
        acc0 = __builtin_amdgcn_mfma_f32_16x16x32_bf16(a, bb0, acc0, 0, 0, 0);
        acc1 = __builtin_amdgcn_mfma_f32_16x16x32_bf16(a, bb1, acc1, 0, 0, 0);
    }

    // C/D layout: col = lane&15, row = (lane>>4)*4 + reg
    int base = b0 + wid * 16;
#pragma unroll
    for (int i = 0; i < 4; ++i) {
        int node = base + grp * 4 + i;
        if (node < NN) {
            y[(size_t)node * COUT + (lane & 15)]      = acc0[i];
            y[(size_t)node * COUT + 16 + (lane & 15)] = acc1[i];
        }
    }
}

// ---------------- fp32 fallback conv (round-0 kernel) ----------------
__global__ __launch_bounds__(256) void conv_kernel(
    const float* __restrict__ x, const int* __restrict__ neigh,
    const float* __restrict__ w, float* __restrict__ y)
{
    int n = blockIdx.x * 256 + threadIdx.x;
    bool valid = (n < NN);
    int nsafe = valid ? n : 0;
    int idx[KK];
#pragma unroll
    for (int k = 0; k < KK; ++k) idx[k] = neigh[(size_t)nsafe * KK + k];
    float acc[COUT];
#pragma unroll
    for (int d = 0; d < COUT; ++d) acc[d] = 0.0f;
    for (int k = 0; k < KK; ++k) {
        const float4* xr = (const float4*)(x + (size_t)idx[k] * CIN);
        float4 xv[8];
#pragma unroll
        for (int j = 0; j < 8; ++j) xv[j] = xr[j];
        const float* wk = w + k * (CIN * COUT);
        const float* xs = (const float*)xv;
#pragma unroll
        for (int c = 0; c < CIN; ++c) {
            float xc = xs[c];
#pragma unroll
            for (int d = 0; d < COUT; ++d)
                acc[d] = fmaf(xc, wk[c * COUT + d], acc[d]);
        }
    }
    if (valid) {
        float4* yr = (float4*)(y + (size_t)n * COUT);
#pragma unroll
        for (int j = 0; j < 8; ++j) {
            float4 v;
            v.x = acc[j*4+0]; v.y = acc[j*4+1]; v.z = acc[j*4+2]; v.w = acc[j*4+3];
            yr[j] = v;
        }
    }
}

// ---------------- per-channel sum / sumsq ----------------
__global__ __launch_bounds__(256) void stats_kernel(
    const float* __restrict__ y, float* __restrict__ ws)
{
    int d = threadIdx.x & 31;
    int rib = threadIdx.x >> 5;
    float s = 0.0f, q = 0.0f;
    for (int r = blockIdx.x * 8 + rib; r < NN; r += gridDim.x * 8) {
        float v = y[(size_t)r * COUT + d];
        s += v;
        q += v * v;
    }
    __shared__ float ls[8][32];
    __shared__ float lq[8][32];
    ls[rib][d] = s;
    lq[rib][d] = q;
    __syncthreads();
    if (threadIdx.x < 32) {
        float S = 0.0f, Q = 0.0f;
#pragma unroll
        for (int i = 0; i < 8; ++i) { S += ls[i][threadIdx.x]; Q += lq[i][threadIdx.x]; }
        atomicAdd(&ws[threadIdx.x], S);
        atomicAdd(&ws[32 + threadIdx.x], Q);
    }
}

// ---------------- finalize scale/shift ----------------
__global__ void finalize_kernel(
    const float* __restrict__ gamma, const float* __restrict__ beta,
    float* __restrict__ ws)
{
    int d = threadIdx.x;
    if (d < 32) {
        float invN = 1.0f / (float)NN;
        float mean = ws[d] * invN;
        float var = ws[32 + d] * invN - mean * mean;
        float rstd = rsqrtf(var + BN_EPS);
        float scale = rstd * gamma[d];
        ws[64 + d] = scale;
        ws[96 + d] = beta[d] - mean * scale;
    }
}

// ---------------- BN + ELU in place ----------------
__global__ __launch_bounds__(256) void bn_elu_kernel(
    float* __restrict__ y, const float* __restrict__ ws)
{
    __shared__ float sc[32], sh[32];
    if (threadIdx.x < 32) {
        sc[threadIdx.x] = ws[64 + threadIdx.x];
        sh[threadIdx.x] = ws[96 + threadIdx.x];
    }
    __syncthreads();
    size_t i = (size_t)blockIdx.x * 256 + threadIdx.x;
    size_t total = (size_t)NN * COUT / 4;
    if (i >= total) return;
    int c0 = (int)((i * 4) & 31);
    float4 v = ((const float4*)y)[i];
    float r[4] = {v.x, v.y, v.z, v.w};
#pragma unroll
    for (int j = 0; j < 4; ++j) {
        float t = r[j] * sc[c0 + j] + sh[c0 + j];
        r[j] = (t > 0.0f) ? t : expm1f(t);
    }
    float4 o; o.x = r[0]; o.y = r[1]; o.z = r[2]; o.w = r[3];
    ((float4*)y)[i] = o;
}

extern "C" void kernel_launch(void* const* d_in, const int* in_sizes, int n_in,
                              void* d_out, int out_size, void* d_ws, size_t ws_size,
                              hipStream_t stream) {
    const float* x     = (const float*)d_in[0];
    const int*   neigh = (const int*)d_in[1];
    const float* w     = (const float*)d_in[2];
    const float* gamma = (const float*)d_in[3];
    const float* beta  = (const float*)d_in[4];
    float* y  = (float*)d_out;
    float* ws = (float*)d_ws;

    hipMemsetAsync(ws, 0, 512, stream);

    if (ws_size >= WS_NEED) {
        unsigned short* wbp = (unsigned short*)((char*)d_ws + WS_WB_OFF);
        unsigned short* xb  = (unsigned short*)((char*)d_ws + WS_XB_OFF);

        size_t cvt_total = (size_t)NN * CIN / 8;
        convert_x_kernel<<<(int)((cvt_total + 255) / 256), 256, 0, stream>>>(x, xb);
        pack_w_kernel<<<(KK * 2 * 64 * 8 + 255) / 256, 256, 0, stream>>>(w, wbp);

        int convBlocks = (NN + 63) / 64;
        conv_mfma_kernel<<<convBlocks, 256, 0, stream>>>(xb, neigh, wbp, y);
    } else {
        int convBlocks = (NN + 255) / 256;
        conv_kernel<<<convBlocks, 256, 0, stream>>>(x, neigh, w, y);
    }

    stats_kernel<<<512, 256, 0, stream>>>(y, ws);
    finalize_kernel<<<1, 32, 0, stream>>>(gamma, beta, ws);

    size_t total4 = (size_t)NN * COUT / 4;
    bn_elu_kernel<<<(int)((total4 + 255) / 256), 256, 0, stream>>>(y, ws);
}

// Round 3
// 160.259 us; speedup vs baseline: 1.9242x; 1.0020x over previous
//
#include <hip/hip_runtime.h>
#include <hip/hip_bf16.h>
#include <math.h>

#define NN 250000
#define CIN 32
#define COUT 32
#define KK 27
#define BN_EPS 1e-5f

typedef __attribute__((ext_vector_type(8))) short bf16x8;
typedef __attribute__((ext_vector_type(4))) float f32x4;

// ws layout (bytes):
//   [0, 512)        stats: ws_f[0..31]=sum, [32..63]=sumsq, [64..95]=scale, [96..127]=shift
//   [512, 55808)    packed bf16 weight: [k][h][lane][j]  (27*2*64*8 ushorts)
//   [65536, +16MB)  bf16 x: [NN][32]
#define WS_WB_OFF   512
#define WS_XB_OFF   65536
#define WS_NEED     (WS_XB_OFF + (size_t)NN * CIN * 2)

#define CVT_CHUNKS  ((NN * CIN) / 8)                     // 1,000,000
#define CVT_BLOCKS  ((CVT_CHUNKS + 255) / 256)           // 3907
#define PACK_ELEMS  (KK * 2 * 64 * 8)                    // 27648
#define PACK_BLOCKS ((PACK_ELEMS + 255) / 256)           // 108

static __device__ __forceinline__ unsigned short f2bf(float f) {
    unsigned int u = __float_as_uint(f);
    unsigned int r = (u + 0x7fffu + ((u >> 16) & 1u)) >> 16;  // RNE
    return (unsigned short)r;
}

// ---------------- prep: convert x -> bf16 AND pack w, one launch ----------------
__global__ __launch_bounds__(256) void prep_kernel(
    const float* __restrict__ x, unsigned short* __restrict__ xb,
    const float* __restrict__ w, unsigned short* __restrict__ wbp)
{
    int b = blockIdx.x;
    if (b < CVT_BLOCKS) {
        size_t i = (size_t)b * 256 + threadIdx.x;
        if (i >= CVT_CHUNKS) return;
        const float4* xp = (const float4*)x;
        float4 a = xp[i * 2], c = xp[i * 2 + 1];
        union { unsigned short u[8]; uint4 v; } o;
        o.u[0] = f2bf(a.x); o.u[1] = f2bf(a.y); o.u[2] = f2bf(a.z); o.u[3] = f2bf(a.w);
        o.u[4] = f2bf(c.x); o.u[5] = f2bf(c.y); o.u[6] = f2bf(c.z); o.u[7] = f2bf(c.w);
        ((uint4*)xb)[i] = o.v;
    } else {
        int tid = (b - CVT_BLOCKS) * 256 + threadIdx.x;
        if (tid >= PACK_ELEMS) return;
        int j = tid & 7;
        int l = (tid >> 3) & 63;
        int h = (tid >> 9) & 1;
        int k = tid >> 10;
        int c = (l >> 4) * 8 + j;
        int d = h * 16 + (l & 15);
        wbp[tid] = f2bf(w[k * (CIN * COUT) + c * COUT + d]);
    }
}

// ---------------- MFMA conv, pipelined: 32 nodes/wave, fused stats ----------------
// k in 9 groups of 3; double-buffered idx->load->mfma pipeline, fully unrolled.
__global__ __launch_bounds__(256, 3) void conv_mfma_kernel(
    const unsigned short* __restrict__ xb,
    const int* __restrict__ neigh,
    const unsigned short* __restrict__ wbp,
    float* __restrict__ y,
    float* __restrict__ ws)
{
    int lane = threadIdx.x & 63;
    int wid  = threadIdx.x >> 6;
    int col  = lane & 15;   // A row within tile / C col (channel within half)
    int grp  = lane >> 4;   // K chunk

    int base = blockIdx.x * 128 + wid * 32;
    int nd[2];
#pragma unroll
    for (int t = 0; t < 2; ++t) {
        int n = base + t * 16 + col;
        nd[t] = (n < NN) ? n : (NN - 1);
    }

    const bf16x8* wbv = (const bf16x8*)wbp;

    int    vidx[2][3][2];
    bf16x8 va[2][3][2];
    bf16x8 vb[2][3][2];
    f32x4  acc[2][2];
#pragma unroll
    for (int t = 0; t < 2; ++t)
#pragma unroll
        for (int h = 0; h < 2; ++h) acc[t][h] = (f32x4){0.f, 0.f, 0.f, 0.f};

#define S0(BUF, G) do {                                                          \
    _Pragma("unroll") for (int kk = 0; kk < 3; ++kk) {                           \
        _Pragma("unroll") for (int t = 0; t < 2; ++t)                            \
            vidx[BUF][kk][t] = neigh[(size_t)nd[t] * KK + (G) * 3 + kk];         \
    } } while (0)

#define S1(BUF, G) do {                                                          \
    _Pragma("unroll") for (int kk = 0; kk < 3; ++kk) {                           \
        _Pragma("unroll") for (int t = 0; t < 2; ++t)                            \
            va[BUF][kk][t] = *(const bf16x8*)(xb + (size_t)vidx[BUF][kk][t] * CIN + grp * 8); \
        _Pragma("unroll") for (int h = 0; h < 2; ++h)                            \
            vb[BUF][kk][h] = wbv[(((G) * 3 + kk) * 2 + h) * 64 + lane];          \
    } } while (0)

#define CG(BUF, G) do {                                                          \
    _Pragma("unroll") for (int kk = 0; kk < 3; ++kk) {                           \
        _Pragma("unroll") for (int t = 0; t < 2; ++t) {                          \
            _Pragma("unroll") for (int h = 0; h < 2; ++h)                        \
                acc[t][h] = __builtin_amdgcn_mfma_f32_16x16x32_bf16(             \
                    va[BUF][kk][t], vb[BUF][kk][h], acc[t][h], 0, 0, 0);         \
        }                                                                        \
    } } while (0)

    S0(0, 0); S1(0, 0); S0(1, 1);
    S1(1, 1); S0(0, 2); CG(0, 0);
    S1(0, 2); S0(1, 3); CG(1, 1);
    S1(1, 3); S0(0, 4); CG(0, 2);
    S1(0, 4); S0(1, 5); CG(1, 3);
    S1(1, 5); S0(0, 6); CG(0, 4);
    S1(0, 6); S0(1, 7); CG(1, 5);
    S1(1, 7); S0(0, 8); CG(0, 6);
    S1(0, 8);           CG(1, 7);
                        CG(0, 8);

#undef S0
#undef S1
#undef CG

    // ---- epilogue: y write + fused per-channel stats ----
    float s0 = 0.f, q0 = 0.f, s1 = 0.f, q1 = 0.f;
#pragma unroll
    for (int t = 0; t < 2; ++t) {
#pragma unroll
        for (int i = 0; i < 4; ++i) {
            int node = base + t * 16 + grp * 4 + i;   // C row = grp*4 + reg
            float v0 = acc[t][0][i], v1 = acc[t][1][i];
            if (node < NN) {
                y[(size_t)node * COUT + col]      = v0;
                y[(size_t)node * COUT + 16 + col] = v1;
                s0 += v0; q0 += v0 * v0;
                s1 += v1; q1 += v1 * v1;
            }
        }
    }
    // reduce over the 4 lane-groups holding the same channel (bits 4,5 of lane)
    s0 += __shfl_xor(s0, 16); s0 += __shfl_xor(s0, 32);
    q0 += __shfl_xor(q0, 16); q0 += __shfl_xor(q0, 32);
    s1 += __shfl_xor(s1, 16); s1 += __shfl_xor(s1, 32);
    q1 += __shfl_xor(q1, 16); q1 += __shfl_xor(q1, 32);

    __shared__ float sred[4][2][16];
    __shared__ float qred[4][2][16];
    if (lane < 16) {
        sred[wid][0][col] = s0; qred[wid][0][col] = q0;
        sred[wid][1][col] = s1; qred[wid][1][col] = q1;
    }
    __syncthreads();
    if (threadIdx.x < 32) {
        int h = threadIdx.x >> 4, c = threadIdx.x & 15;
        float S = 0.f, Q = 0.f;
#pragma unroll
        for (int wv = 0; wv < 4; ++wv) { S += sred[wv][h][c]; Q += qred[wv][h][c]; }
        atomicAdd(&ws[h * 16 + c], S);
        atomicAdd(&ws[32 + h * 16 + c], Q);
    }
}

// ---------------- fp32 fallback conv + stats (ws too small) ----------------
__global__ __launch_bounds__(256) void conv_kernel(
    const float* __restrict__ x, const int* __restrict__ neigh,
    const float* __restrict__ w, float* __restrict__ y)
{
    int n = blockIdx.x * 256 + threadIdx.x;
    bool valid = (n < NN);
    int nsafe = valid ? n : 0;
    int idx[KK];
#pragma unroll
    for (int k = 0; k < KK; ++k) idx[k] = neigh[(size_t)nsafe * KK + k];
    float acc[COUT];
#pragma unroll
    for (int d = 0; d < COUT; ++d) acc[d] = 0.0f;
    for (int k = 0; k < KK; ++k) {
        const float4* xr = (const float4*)(x + (size_t)idx[k] * CIN);
        float4 xv[8];
#pragma unroll
        for (int j = 0; j < 8; ++j) xv[j] = xr[j];
        const float* wk = w + k * (CIN * COUT);
        const float* xs = (const float*)xv;
#pragma unroll
        for (int c = 0; c < CIN; ++c) {
            float xc = xs[c];
#pragma unroll
            for (int d = 0; d < COUT; ++d)
                acc[d] = fmaf(xc, wk[c * COUT + d], acc[d]);
        }
    }
    if (valid) {
        float4* yr = (float4*)(y + (size_t)n * COUT);
#pragma unroll
        for (int j = 0; j < 8; ++j) {
            float4 v;
            v.x = acc[j*4+0]; v.y = acc[j*4+1]; v.z = acc[j*4+2]; v.w = acc[j*4+3];
            yr[j] = v;
        }
    }
}

__global__ __launch_bounds__(256) void stats_kernel(
    const float* __restrict__ y, float* __restrict__ ws)
{
    int d = threadIdx.x & 31;
    int rib = threadIdx.x >> 5;
    float s = 0.0f, q = 0.0f;
    for (int r = blockIdx.x * 8 + rib; r < NN; r += gridDim.x * 8) {
        float v = y[(size_t)r * COUT + d];
        s += v;
        q += v * v;
    }
    __shared__ float ls[8][32];
    __shared__ float lq[8][32];
    ls[rib][d] = s;
    lq[rib][d] = q;
    __syncthreads();
    if (threadIdx.x < 32) {
        float S = 0.0f, Q = 0.0f;
#pragma unroll
        for (int i = 0; i < 8; ++i) { S += ls[i][threadIdx.x]; Q += lq[i][threadIdx.x]; }
        atomicAdd(&ws[threadIdx.x], S);
        atomicAdd(&ws[32 + threadIdx.x], Q);
    }
}

// ---------------- finalize scale/shift ----------------
__global__ void finalize_kernel(
    const float* __restrict__ gamma, const float* __restrict__ beta,
    float* __restrict__ ws)
{
    int d = threadIdx.x;
    if (d < 32) {
        float invN = 1.0f / (float)NN;
        float mean = ws[d] * invN;
        float var = ws[32 + d] * invN - mean * mean;
        float rstd = rsqrtf(var + BN_EPS);
        float scale = rstd * gamma[d];
        ws[64 + d] = scale;
        ws[96 + d] = beta[d] - mean * scale;
    }
}

// ---------------- BN + ELU in place ----------------
__global__ __launch_bounds__(256) void bn_elu_kernel(
    float* __restrict__ y, const float* __restrict__ ws)
{
    __shared__ float sc[32], sh[32];
    if (threadIdx.x < 32) {
        sc[threadIdx.x] = ws[64 + threadIdx.x];
        sh[threadIdx.x] = ws[96 + threadIdx.x];
    }
    __syncthreads();
    size_t i = (size_t)blockIdx.x * 256 + threadIdx.x;
    size_t total = (size_t)NN * COUT / 4;
    if (i >= total) return;
    int c0 = (int)((i * 4) & 31);
    float4 v = ((const float4*)y)[i];
    float r[4] = {v.x, v.y, v.z, v.w};
#pragma unroll
    for (int j = 0; j < 4; ++j) {
        float t = r[j] * sc[c0 + j] + sh[c0 + j];
        r[j] = (t > 0.0f) ? t : expm1f(t);
    }
    float4 o; o.x = r[0]; o.y = r[1]; o.z = r[2]; o.w = r[3];
    ((float4*)y)[i] = o;
}

extern "C" void kernel_launch(void* const* d_in, const int* in_sizes, int n_in,
                              void* d_out, int out_size, void* d_ws, size_t ws_size,
                              hipStream_t stream) {
    const float* x     = (const float*)d_in[0];
    const int*   neigh = (const int*)d_in[1];
    const float* w     = (const float*)d_in[2];
    const float* gamma = (const float*)d_in[3];
    const float* beta  = (const float*)d_in[4];
    float* y  = (float*)d_out;
    float* ws = (float*)d_ws;

    hipMemsetAsync(ws, 0, 512, stream);

    if (ws_size >= WS_NEED) {
        unsigned short* wbp = (unsigned short*)((char*)d_ws + WS_WB_OFF);
        unsigned short* xb  = (unsigned short*)((char*)d_ws + WS_XB_OFF);

        prep_kernel<<<CVT_BLOCKS + PACK_BLOCKS, 256, 0, stream>>>(x, xb, w, wbp);

        int convBlocks = (NN + 127) / 128;
        conv_mfma_kernel<<<convBlocks, 256, 0, stream>>>(xb, neigh, wbp, y, ws);
    } else {
        int convBlocks = (NN + 255) / 256;
        conv_kernel<<<convBlocks, 256, 0, stream>>>(x, neigh, w, y);
        stats_kernel<<<512, 256, 0, stream>>>(y, ws);
    }

    finalize_kernel<<<1, 32, 0, stream>>>(gamma, beta, ws);

    size_t total4 = (size_t)NN * COUT / 4;
    bn_elu_kernel<<<(int)((total4 + 255) / 256), 256, 0, stream>>>(y, ws);
}